// Round 1
// 480.576 us; speedup vs baseline: 1.0420x; 1.0420x over previous
//
#include <hip/hip_runtime.h>
#include <stdint.h>

#define N_NODES 8192
#define CH 256
#define MT 32
#define BK 64
#define KB_COUNT 128
#define NSTAGE 4
#define ZROWS 16
#define ZBLOCKS (N_NODES / ZROWS)  // 512
#define DEGBLOCKS (N_NODES / 4)    // 2048

typedef __bf16 bf16x8 __attribute__((ext_vector_type(8)));
typedef float f32x4 __attribute__((ext_vector_type(4)));
typedef unsigned short u16x4 __attribute__((ext_vector_type(4)));

// ---- async global->LDS, 16B per lane. LDS dest is the WAVE-UNIFORM base;
// HW scatters lane l to base + 16*l.
__device__ __forceinline__ void async_copy16(const void* g, void* l) {
  __builtin_amdgcn_global_load_lds(
      (const __attribute__((address_space(1))) void*)(uintptr_t)g,
      (__attribute__((address_space(3))) void*)(uint32_t)(uintptr_t)l,
      16, 0, 0);
}

__device__ __forceinline__ unsigned short f32_to_bf16_rne(float f) {
  unsigned u = __float_as_uint(f);
  u += 0x7FFFu + ((u >> 16) & 1u);
  return (unsigned short)(u >> 16);
}

__device__ __forceinline__ u16x4 f32x4_to_bf16_rne(f32x4 v) {
  u16x4 r;
  r.x = f32_to_bf16_rne(v.x);
  r.y = f32_to_bf16_rne(v.y);
  r.z = f32_to_bf16_rne(v.z);
  r.w = f32_to_bf16_rne(v.w);
  return r;
}

// ---- Pass 1 (heterogeneous blocks):
//   blocks [0, ZBLOCKS):           z = x @ w  (fp32, 16 rows/block)
//   blocks [ZBLOCKS, ZBLOCKS+2048): deg rowsums (4 rows/block, wave-per-row)
//                                   + write adj as bf16 (RNE) to adjb
__global__ void __launch_bounds__(256) k_pass1(const float* __restrict__ x,
                                               const float* __restrict__ w,
                                               const float* __restrict__ adj,
                                               float* __restrict__ z,
                                               float* __restrict__ dsq,
                                               unsigned short* __restrict__ adjb) {
  __shared__ float xs[ZROWS][CH];
  if (blockIdx.x < ZBLOCKS) {
    const int r0 = blockIdx.x * ZROWS;
    const int t = threadIdx.x;
#pragma unroll
    for (int r = 0; r < ZROWS; ++r) xs[r][t] = x[(size_t)(r0 + r) * CH + t];
    __syncthreads();
    float acc[ZROWS];
#pragma unroll
    for (int r = 0; r < ZROWS; ++r) acc[r] = 0.f;
    for (int k = 0; k < CH; k += 8) {
      float wv[8];
#pragma unroll
      for (int u = 0; u < 8; ++u) wv[u] = w[(size_t)(k + u) * CH + t];
#pragma unroll
      for (int r = 0; r < ZROWS; ++r) {
#pragma unroll
        for (int u = 0; u < 8; ++u) acc[r] += xs[r][k + u] * wv[u];
      }
    }
#pragma unroll
    for (int r = 0; r < ZROWS; ++r) z[(size_t)(r0 + r) * CH + t] = acc[r];
  } else {
    const int wave = threadIdx.x >> 6, lane = threadIdx.x & 63;
    const int row = (blockIdx.x - ZBLOCKS) * 4 + wave;
    const f32x4* ar = (const f32x4*)(adj + (size_t)row * N_NODES);
    u16x4* br = (u16x4*)(adjb + (size_t)row * N_NODES);
    float s0 = 0.f, s1 = 0.f, s2 = 0.f, s3 = 0.f;
#pragma unroll
    for (int i = 0; i < 8; ++i) {
      f32x4 a = ar[lane + 64 * (4 * i + 0)];
      f32x4 b = ar[lane + 64 * (4 * i + 1)];
      f32x4 c = ar[lane + 64 * (4 * i + 2)];
      f32x4 d = ar[lane + 64 * (4 * i + 3)];
      br[lane + 64 * (4 * i + 0)] = f32x4_to_bf16_rne(a);
      br[lane + 64 * (4 * i + 1)] = f32x4_to_bf16_rne(b);
      br[lane + 64 * (4 * i + 2)] = f32x4_to_bf16_rne(c);
      br[lane + 64 * (4 * i + 3)] = f32x4_to_bf16_rne(d);
      s0 += (a.x + a.y) + (a.z + a.w);
      s1 += (b.x + b.y) + (b.z + b.w);
      s2 += (c.x + c.y) + (c.z + c.w);
      s3 += (d.x + d.y) + (d.z + d.w);
    }
    float s = (s0 + s1) + (s2 + s3);
#pragma unroll
    for (int off = 32; off > 0; off >>= 1) s += __shfl_down(s, off, 64);
    if (lane == 0) dsq[row] = rsqrtf(s + 1.0f);
  }
}

// ---- Pass 2: yt[c][j] = bf16(dsq[j] * z[j][c])  (transposed, k-contiguous)
__global__ void __launch_bounds__(256) k_y(const float* __restrict__ z,
                                           const float* __restrict__ dsq,
                                           unsigned short* __restrict__ yt) {
  const int r0 = blockIdx.x * 16;
  const int t = threadIdx.x;
  unsigned short vals[16];
#pragma unroll
  for (int r = 0; r < 16; ++r)
    vals[r] = f32_to_bf16_rne(dsq[r0 + r] * z[(size_t)(r0 + r) * CH + t]);
  // 16 consecutive bf16 per lane -> four 8B stores (32B contiguous per lane)
  *(u16x4*)&yt[(size_t)t * N_NODES + r0 + 0] = *(u16x4*)&vals[0];
  *(u16x4*)&yt[(size_t)t * N_NODES + r0 + 4] = *(u16x4*)&vals[4];
  *(u16x4*)&yt[(size_t)t * N_NODES + r0 + 8] = *(u16x4*)&vals[8];
  *(u16x4*)&yt[(size_t)t * N_NODES + r0 + 12] = *(u16x4*)&vals[12];
}

// ---- Pass 3: S = adjb @ y ; out = elu(dsq_i*(S + dsq_i*z_i))
// 512 threads / 8 waves (2 per SIMD), each wave owns 32 cols. MT=32 rows, full K.
// NEW: 4-stage LDS ring + counted vmcnt waits (T3+T4). 3 tiles stay in flight
// across the barrier; no vmcnt(0) drain in the main loop. Each wave waits for
// ITS OWN tile-t DMAs (A-stagers have 5/tile, others 4/tile), then s_barrier
// publishes tile t to all waves. Buffer (t+3)&3 == (t-1)&3 is re-issued only
// after the barrier that proves all waves finished compute(t-1).
__global__ void __launch_bounds__(512, 1) k_gemm1(const unsigned short* __restrict__ adjb,
                                                  const unsigned short* __restrict__ yt,
                                                  const float* __restrict__ z,
                                                  const float* __restrict__ dsq,
                                                  float* __restrict__ out) {
  __shared__ __align__(16) unsigned short As[NSTAGE][MT * BK];  // 4 KB each  (16 KB)
  __shared__ __align__(16) unsigned short Bs[NSTAGE][CH * BK];  // 32 KB each (128 KB)

  const int tid = threadIdx.x;
  const int wave = tid >> 6;  // 0..7
  const int lane = tid & 63;
  const int m0 = blockIdx.x * MT;
  const int lr = lane & 15;
  const int lq = lane >> 4;

  // A staging: tile = 256 chunks of 16B = 4 wave-instrs; waves 0..3 get one each.
  // instr i covers LDS chunks p = 64i+l: r = p>>3, c8 = (l&7)^(r&7)  (XOR swizzle).
  const bool hasA = wave < 4;
  const unsigned short* ag;
  int aoffu;
  {
    int i = hasA ? wave : 0;
    int p = 64 * i + lane;
    int r = p >> 3;
    int c8 = (lane & 7) ^ (r & 7);
    ag = adjb + (size_t)(m0 + r) * N_NODES + c8 * 8;
    aoffu = 1024 * i;
  }
  // B staging: 32 instrs, 4 per wave; wave w stages exactly its n-slice [32w,32w+32).
  const unsigned short* bg[4];
  int boffu[4];
#pragma unroll
  for (int q = 0; q < 4; ++q) {
    int i = wave * 4 + q;
    int p = 64 * i + lane;
    int n = p >> 3;
    int c8 = (lane & 7) ^ (n & 7);
    bg[q] = yt + (size_t)n * N_NODES + c8 * 8;
    boffu[q] = 1024 * i;
  }

  f32x4 acc[2][2];
#pragma unroll
  for (int i = 0; i < 2; ++i)
#pragma unroll
    for (int j = 0; j < 2; ++j) acc[i][j] = (f32x4){0.f, 0.f, 0.f, 0.f};

  auto issue = [&](int b, int k0) {
    char* aL = (char*)&As[b][0];
    char* bL = (char*)&Bs[b][0];
    if (hasA) async_copy16(ag + k0, aL + aoffu);
#pragma unroll
    for (int q = 0; q < 4; ++q) async_copy16(bg[q] + k0, bL + boffu[q]);
  };

  auto compute = [&](int b) {
    const char* aB = (const char*)&As[b][0];
    const char* bB = (const char*)&Bs[b][0];
#pragma unroll
    for (int k32 = 0; k32 < 2; ++k32) {
      bf16x8 afr[2];
#pragma unroll
      for (int mt = 0; mt < 2; ++mt) {
        int row = mt * 16 + lr;
        int c8 = k32 * 4 + lq;
        int p = row * 8 + (c8 ^ (row & 7));
        afr[mt] = *(const bf16x8*)(aB + p * 16);
      }
      __builtin_amdgcn_s_setprio(1);
#pragma unroll
      for (int nt = 0; nt < 2; ++nt) {
        int n = wave * 32 + nt * 16 + lr;
        int c8 = k32 * 4 + lq;
        int p = n * 8 + (c8 ^ (n & 7));
        bf16x8 bfr = *(const bf16x8*)(bB + p * 16);
        acc[0][nt] = __builtin_amdgcn_mfma_f32_16x16x32_bf16(afr[0], bfr, acc[0][nt], 0, 0, 0);
        acc[1][nt] = __builtin_amdgcn_mfma_f32_16x16x32_bf16(afr[1], bfr, acc[1][nt], 0, 0, 0);
      }
      __builtin_amdgcn_s_setprio(0);
    }
  };

  // Prologue: 3 tiles in flight.
  issue(0, 0);
  issue(1, BK);
  issue(2, 2 * BK);

  // Steady state: wait(own tile-t loads done) -> barrier -> issue(t+3) -> compute(t).
  // hasA waves: 5 DMAs/tile -> keep 2 tiles in flight = vmcnt(10); others vmcnt(8).
  for (int kb = 0; kb < KB_COUNT - 2; ++kb) {
    if (hasA) asm volatile("s_waitcnt vmcnt(10)" ::: "memory");
    else      asm volatile("s_waitcnt vmcnt(8)"  ::: "memory");
    __builtin_amdgcn_s_barrier();
    __builtin_amdgcn_sched_barrier(0);
    if (kb + 3 < KB_COUNT) issue((kb + 3) & (NSTAGE - 1), (kb + 3) * BK);
    compute(kb & (NSTAGE - 1));
    __builtin_amdgcn_sched_barrier(0);
  }
  // Drain tail: kb = KB_COUNT-2 (one tile still in flight), then kb = KB_COUNT-1.
  if (hasA) asm volatile("s_waitcnt vmcnt(5)" ::: "memory");
  else      asm volatile("s_waitcnt vmcnt(4)" ::: "memory");
  __builtin_amdgcn_s_barrier();
  __builtin_amdgcn_sched_barrier(0);
  compute((KB_COUNT - 2) & (NSTAGE - 1));
  __builtin_amdgcn_sched_barrier(0);
  asm volatile("s_waitcnt vmcnt(0)" ::: "memory");
  __builtin_amdgcn_s_barrier();
  __builtin_amdgcn_sched_barrier(0);
  compute((KB_COUNT - 1) & (NSTAGE - 1));

  // epilogue: out[i][c] = elu(dsq_i * (acc + dsq_i * z[i][c]))
#pragma unroll
  for (int mt = 0; mt < 2; ++mt) {
#pragma unroll
    for (int r = 0; r < 4; ++r) {
      int row = m0 + mt * 16 + lq * 4 + r;
      float di = dsq[row];
#pragma unroll
      for (int nt = 0; nt < 2; ++nt) {
        int col = wave * 32 + nt * 16 + lr;
        float v = acc[mt][nt][r];
        v = di * (v + di * z[(size_t)row * CH + col]);
        v = v > 0.f ? v : expm1f(v);
        out[(size_t)row * CH + col] = v;
      }
    }
  }
}

extern "C" void kernel_launch(void* const* d_in, const int* in_sizes, int n_in,
                              void* d_out, int out_size, void* d_ws, size_t ws_size,
                              hipStream_t stream) {
  const float* x = (const float*)d_in[0];
  const float* adj = (const float*)d_in[1];
  const float* w = (const float*)d_in[2];
  float* out = (float*)d_out;

  // ws layout: dsq @0 (32KB slot) ; yt @32768 (4MB) ; z @4227072 (8MB) ;
  //            adjb @12615680 (134MB)
  float* dsq = (float*)d_ws;
  unsigned short* yt = (unsigned short*)((char*)d_ws + 32768);
  float* z = (float*)((char*)d_ws + 4227072);
  unsigned short* adjb = (unsigned short*)((char*)d_ws + 12615680);

  k_pass1<<<ZBLOCKS + DEGBLOCKS, 256, 0, stream>>>(x, w, adj, z, dsq, adjb);
  k_y<<<N_NODES / 16, 256, 0, stream>>>(z, dsq, yt);
  k_gemm1<<<N_NODES / MT, 512, 0, stream>>>(adjb, yt, z, dsq, out);
}

// Round 2
// 444.638 us; speedup vs baseline: 1.1262x; 1.0808x over previous
//
#include <hip/hip_runtime.h>
#include <stdint.h>

#define N_NODES 8192
#define CH 256
#define BM 128
#define BK 64
#define KSPLIT 4
#define KLEN (N_NODES / KSPLIT)  // 2048
#define TILES (KLEN / BK)        // 32
#define NSTAGE 3
#define ZROWS 16
#define ZBLOCKS (N_NODES / ZROWS)  // 512
#define DEGBLOCKS (N_NODES / 4)    // 2048

typedef __bf16 bf16x8 __attribute__((ext_vector_type(8)));
typedef float f32x4 __attribute__((ext_vector_type(4)));
typedef unsigned short u16x4 __attribute__((ext_vector_type(4)));

// ---- async global->LDS, 16B per lane. LDS dest is the WAVE-UNIFORM base;
// HW scatters lane l to base + 16*l.
__device__ __forceinline__ void async_copy16(const void* g, void* l) {
  __builtin_amdgcn_global_load_lds(
      (const __attribute__((address_space(1))) void*)(uintptr_t)g,
      (__attribute__((address_space(3))) void*)(uint32_t)(uintptr_t)l,
      16, 0, 0);
}

__device__ __forceinline__ unsigned short f32_to_bf16_rne(float f) {
  unsigned u = __float_as_uint(f);
  u += 0x7FFFu + ((u >> 16) & 1u);
  return (unsigned short)(u >> 16);
}

__device__ __forceinline__ u16x4 f32x4_to_bf16_rne(f32x4 v) {
  u16x4 r;
  r.x = f32_to_bf16_rne(v.x);
  r.y = f32_to_bf16_rne(v.y);
  r.z = f32_to_bf16_rne(v.z);
  r.w = f32_to_bf16_rne(v.w);
  return r;
}

// ---- Pass 1 (heterogeneous blocks):
//   blocks [0, ZBLOCKS):           z = x @ w  (fp32, 16 rows/block)
//   blocks [ZBLOCKS, ZBLOCKS+2048): deg rowsums (4 rows/block, wave-per-row)
//                                   + write adj as bf16 (RNE) to adjb
__global__ void __launch_bounds__(256) k_pass1(const float* __restrict__ x,
                                               const float* __restrict__ w,
                                               const float* __restrict__ adj,
                                               float* __restrict__ z,
                                               float* __restrict__ dsq,
                                               unsigned short* __restrict__ adjb) {
  __shared__ float xs[ZROWS][CH];
  if (blockIdx.x < ZBLOCKS) {
    const int r0 = blockIdx.x * ZROWS;
    const int t = threadIdx.x;
#pragma unroll
    for (int r = 0; r < ZROWS; ++r) xs[r][t] = x[(size_t)(r0 + r) * CH + t];
    __syncthreads();
    float acc[ZROWS];
#pragma unroll
    for (int r = 0; r < ZROWS; ++r) acc[r] = 0.f;
    for (int k = 0; k < CH; k += 8) {
      float wv[8];
#pragma unroll
      for (int u = 0; u < 8; ++u) wv[u] = w[(size_t)(k + u) * CH + t];
#pragma unroll
      for (int r = 0; r < ZROWS; ++r) {
#pragma unroll
        for (int u = 0; u < 8; ++u) acc[r] += xs[r][k + u] * wv[u];
      }
    }
#pragma unroll
    for (int r = 0; r < ZROWS; ++r) z[(size_t)(r0 + r) * CH + t] = acc[r];
  } else {
    const int wave = threadIdx.x >> 6, lane = threadIdx.x & 63;
    const int row = (blockIdx.x - ZBLOCKS) * 4 + wave;
    const f32x4* ar = (const f32x4*)(adj + (size_t)row * N_NODES);
    u16x4* br = (u16x4*)(adjb + (size_t)row * N_NODES);
    float s0 = 0.f, s1 = 0.f, s2 = 0.f, s3 = 0.f;
#pragma unroll
    for (int i = 0; i < 8; ++i) {
      f32x4 a = ar[lane + 64 * (4 * i + 0)];
      f32x4 b = ar[lane + 64 * (4 * i + 1)];
      f32x4 c = ar[lane + 64 * (4 * i + 2)];
      f32x4 d = ar[lane + 64 * (4 * i + 3)];
      br[lane + 64 * (4 * i + 0)] = f32x4_to_bf16_rne(a);
      br[lane + 64 * (4 * i + 1)] = f32x4_to_bf16_rne(b);
      br[lane + 64 * (4 * i + 2)] = f32x4_to_bf16_rne(c);
      br[lane + 64 * (4 * i + 3)] = f32x4_to_bf16_rne(d);
      s0 += (a.x + a.y) + (a.z + a.w);
      s1 += (b.x + b.y) + (b.z + b.w);
      s2 += (c.x + c.y) + (c.z + c.w);
      s3 += (d.x + d.y) + (d.z + d.w);
    }
    float s = (s0 + s1) + (s2 + s3);
#pragma unroll
    for (int off = 32; off > 0; off >>= 1) s += __shfl_down(s, off, 64);
    if (lane == 0) dsq[row] = rsqrtf(s + 1.0f);
  }
}

// ---- Pass 2: yt[c][j] = bf16(dsq[j] * z[j][c])  (transposed, k-contiguous)
__global__ void __launch_bounds__(256) k_y(const float* __restrict__ z,
                                           const float* __restrict__ dsq,
                                           unsigned short* __restrict__ yt) {
  const int r0 = blockIdx.x * 16;
  const int t = threadIdx.x;
  unsigned short vals[16];
#pragma unroll
  for (int r = 0; r < 16; ++r)
    vals[r] = f32_to_bf16_rne(dsq[r0 + r] * z[(size_t)(r0 + r) * CH + t]);
  *(u16x4*)&yt[(size_t)t * N_NODES + r0 + 0] = *(u16x4*)&vals[0];
  *(u16x4*)&yt[(size_t)t * N_NODES + r0 + 4] = *(u16x4*)&vals[4];
  *(u16x4*)&yt[(size_t)t * N_NODES + r0 + 8] = *(u16x4*)&vals[8];
  *(u16x4*)&yt[(size_t)t * N_NODES + r0 + 12] = *(u16x4*)&vals[12];
}

// ---- Pass 3: partial[s] = adjb[:, sK:(s+1)K] @ y[sK:(s+1)K, :]
// BM=128 x 256 output per block, K-split 4 ways -> grid 256 = 1 block/CU.
// s = blockIdx.x & 3: all 32 blocks on an XCD share ONE phase-locked 1MB yt
// slice -> L2-resident B. 8 waves in 2x4 grid, each owns 64x64 output
// (acc 4x4 f32x4). NSTAGE=3 ring (144KB LDS), uniform 6 DMAs/wave/tile,
// counted vmcnt(6): 1 tile in flight across the barrier; buffer t+2 == t-1
// was proven drained by barrier t (compute t-1's lgkm waits precede it).
__global__ void __launch_bounds__(512, 1) k_gemm1(const unsigned short* __restrict__ adjb,
                                                  const unsigned short* __restrict__ yt,
                                                  float* __restrict__ part) {
  __shared__ __align__(16) unsigned short As[NSTAGE][BM * BK];  // 16 KB each
  __shared__ __align__(16) unsigned short Bs[NSTAGE][CH * BK];  // 32 KB each

  const int tid = threadIdx.x;
  const int wave = tid >> 6;  // 0..7
  const int lane = tid & 63;
  const int s = blockIdx.x & 3;
  const int m0 = (blockIdx.x >> 2) * BM;
  const int k_base = s * KLEN;
  const int lr = lane & 15;
  const int lq = lane >> 4;
  const int wr = wave >> 2;  // 0..1 (m-dir)
  const int wc = wave & 3;   // 0..3 (n-dir)

  // A staging: tile = 1024 chunks of 16B = 16 wave-instrs; wave w does 2w,2w+1.
  // instr i covers LDS chunks p = 64i+l: r = p>>3 (8 lanes/row = 128B contig),
  // swizzled source chunk c8 = (l&7)^(r&7).
  const unsigned short* ag[2];
  int aoff[2];
#pragma unroll
  for (int q = 0; q < 2; ++q) {
    int i = wave * 2 + q;
    int p = 64 * i + lane;
    int r = p >> 3;
    int c8 = (lane & 7) ^ (r & 7);
    ag[q] = adjb + (size_t)(m0 + r) * N_NODES + k_base + c8 * 8;
    aoff[q] = 1024 * i;
  }
  // B staging: 32 instrs, 4 per wave.
  const unsigned short* bg[4];
  int boff[4];
#pragma unroll
  for (int q = 0; q < 4; ++q) {
    int i = wave * 4 + q;
    int p = 64 * i + lane;
    int n = p >> 3;
    int c8 = (lane & 7) ^ (n & 7);
    bg[q] = yt + (size_t)n * N_NODES + k_base + c8 * 8;
    boff[q] = 1024 * i;
  }

  f32x4 acc[4][4];
#pragma unroll
  for (int i = 0; i < 4; ++i)
#pragma unroll
    for (int j = 0; j < 4; ++j) acc[i][j] = (f32x4){0.f, 0.f, 0.f, 0.f};

  auto issue = [&](int b, int k0) {
    char* aL = (char*)&As[b][0];
    char* bL = (char*)&Bs[b][0];
#pragma unroll
    for (int q = 0; q < 2; ++q) async_copy16(ag[q] + k0, aL + aoff[q]);
#pragma unroll
    for (int q = 0; q < 4; ++q) async_copy16(bg[q] + k0, bL + boff[q]);
  };

  auto compute = [&](int b) {
    const char* aB = (const char*)&As[b][0];
    const char* bB = (const char*)&Bs[b][0];
#pragma unroll
    for (int k32 = 0; k32 < 2; ++k32) {
      const int c8 = k32 * 4 + lq;
      bf16x8 afr[4];
#pragma unroll
      for (int mt = 0; mt < 4; ++mt) {
        int row = wr * 64 + mt * 16 + lr;
        int p = row * 8 + (c8 ^ (row & 7));
        afr[mt] = *(const bf16x8*)(aB + p * 16);
      }
      __builtin_amdgcn_s_setprio(1);
#pragma unroll
      for (int nt = 0; nt < 4; ++nt) {
        int n = wc * 64 + nt * 16 + lr;
        int p = n * 8 + (c8 ^ (n & 7));
        bf16x8 bfr = *(const bf16x8*)(bB + p * 16);
#pragma unroll
        for (int mt = 0; mt < 4; ++mt)
          acc[mt][nt] = __builtin_amdgcn_mfma_f32_16x16x32_bf16(afr[mt], bfr, acc[mt][nt], 0, 0, 0);
      }
      __builtin_amdgcn_s_setprio(0);
    }
  };

  // Prologue: 2 tiles in flight (tile t lives in buffer t % 3).
  issue(0, 0);
  issue(1, BK);

  int bc = 0;  // buffer of tile kb
  for (int kb = 0; kb < TILES - 1; ++kb) {
    // in-flight: tiles kb, kb+1 (12 DMAs for this wave); wait for kb's 6.
    asm volatile("s_waitcnt vmcnt(6)" ::: "memory");
    __builtin_amdgcn_s_barrier();
    __builtin_amdgcn_sched_barrier(0);
    if (kb + 2 < TILES) {
      int bi = bc + 2;
      if (bi >= NSTAGE) bi -= NSTAGE;
      issue(bi, (kb + 2) * BK);
    }
    compute(bc);
    __builtin_amdgcn_sched_barrier(0);
    bc = (bc + 1 == NSTAGE) ? 0 : bc + 1;
  }
  asm volatile("s_waitcnt vmcnt(0)" ::: "memory");
  __builtin_amdgcn_s_barrier();
  __builtin_amdgcn_sched_barrier(0);
  compute(bc);

  // store f32 partials (quarter-wave coalesced 64B groups)
  float* Ps = part + (size_t)s * N_NODES * CH;
#pragma unroll
  for (int mt = 0; mt < 4; ++mt) {
#pragma unroll
    for (int r = 0; r < 4; ++r) {
      int row = m0 + wr * 64 + mt * 16 + lq * 4 + r;
#pragma unroll
      for (int nt = 0; nt < 4; ++nt) {
        int col = wc * 64 + nt * 16 + lr;
        Ps[(size_t)row * CH + col] = acc[mt][nt][r];
      }
    }
  }
}

// ---- Pass 4: out = elu(dsq_i * (sum_s part[s] + dsq_i * z_i))
__global__ void __launch_bounds__(256) k_fin(const float* __restrict__ part,
                                             const float* __restrict__ z,
                                             const float* __restrict__ dsq,
                                             float* __restrict__ out) {
  const int r0 = blockIdx.x * 16;
  const int t = threadIdx.x;
  const size_t SP = (size_t)N_NODES * CH;
#pragma unroll
  for (int r = 0; r < 16; ++r) {
    const int row = r0 + r;
    const size_t idx = (size_t)row * CH + t;
    float sum = (part[idx] + part[idx + SP]) + (part[idx + 2 * SP] + part[idx + 3 * SP]);
    float di = dsq[row];
    float v = di * (sum + di * z[idx]);
    v = v > 0.f ? v : expm1f(v);
    out[idx] = v;
  }
}

extern "C" void kernel_launch(void* const* d_in, const int* in_sizes, int n_in,
                              void* d_out, int out_size, void* d_ws, size_t ws_size,
                              hipStream_t stream) {
  const float* x = (const float*)d_in[0];
  const float* adj = (const float*)d_in[1];
  const float* w = (const float*)d_in[2];
  float* out = (float*)d_out;

  // ws layout: dsq @0 (32KB slot) ; yt @32768 (4MB) ; z @4227072 (8MB) ;
  //            adjb @12615680 (134MB) ; part @146833408 (32MB)
  float* dsq = (float*)d_ws;
  unsigned short* yt = (unsigned short*)((char*)d_ws + 32768);
  float* z = (float*)((char*)d_ws + 4227072);
  unsigned short* adjb = (unsigned short*)((char*)d_ws + 12615680);
  float* part = (float*)((char*)d_ws + 146833408);

  k_pass1<<<ZBLOCKS + DEGBLOCKS, 256, 0, stream>>>(x, w, adj, z, dsq, adjb);
  k_y<<<N_NODES / 16, 256, 0, stream>>>(z, dsq, yt);
  k_gemm1<<<N_NODES / BM * KSPLIT, 512, 0, stream>>>(adjb, yt, part);
  k_fin<<<N_NODES / 16, 256, 0, stream>>>(part, z, dsq, out);
}